// Round 5
// baseline (327.974 us; speedup 1.0000x reference)
//
#include <hip/hip_runtime.h>
#include <math.h>

// Problem constants
#define V_ 25
#define C_ 64
#define D_ 64
#define N_ 64
#define T_ 300
#define R_ (N_*T_)      // 19200 rows
#define K_ (V_*C_)      // 1600
#define BN_EPS 1e-5f

// Workspace layout (4-byte units) — total 26048 f32 = 104 KB
#define WS_GM    0       // (bf16(mask)<<16) | lds_off, k order       [1600] u32
#define WS_SUM   1600    // sum_y per (v,d) flat jj                   [1600] f32
#define WS_SQ    3200    // sumsq_y per (v,d) flat jj (contig!)       [1600] f32
#define WS_WBF   4800    // W as bf16                                 [4096] u16 = 2048 f32
#define WS_SC2   6848    // BN scale, rem-order e = dd*100+rem        [6400] f32
#define WS_SH2   13248   // BN shift, rem-order                      [6400] f32
#define WS_YO    19648   // precomputed y_lds offset, rem-order      [6400] u32

#define P1_GRID  512     // pass1 persistent blocks (dbuf pipeline)
#define P2_GRID  768     // pass2 persistent blocks (3/CU x 256)
#define NWIN     4800    // R_/4

using bf16x8 = __attribute__((ext_vector_type(8))) short;
using f32x4  = __attribute__((ext_vector_type(4))) float;
using i32x4  = __attribute__((ext_vector_type(4))) int;

__device__ __forceinline__ unsigned short f2bf(float f) {
    unsigned u = __float_as_uint(f);
    return (unsigned short)((u + 0x7FFFu + ((u >> 16) & 1u)) >> 16);
}

// HW packed f32->bf16 convert (RNE), 1 inst replaces ~12. No builtin on gfx950.
__device__ __forceinline__ unsigned cvt_pk_bf16(float lo, float hi) {
    unsigned r;
    asm("v_cvt_pk_bf16_f32 %0, %1, %2" : "=v"(r) : "v"(lo), "v"(hi));
    return r;
}

// async global->LDS, 16B per active lane. Dest must be uniform-base + lane*16
// (holds for all call sites: lds index = i*256 + w*64 + lane).
__device__ __forceinline__ void gload16(const void* g, void* l) {
    __builtin_amdgcn_global_load_lds(
        (const __attribute__((address_space(1))) void*)g,
        (__attribute__((address_space(3))) void*)l, 16, 0, 0);
}

// LDS-only barrier: make ds ops visible without draining vmcnt (keeps the
// global_load_lds prefetch in flight). Rule-18 pattern: sched_barrier after wait.
__device__ __forceinline__ void barrier_lds() {
    asm volatile("s_waitcnt lgkmcnt(0)" ::: "memory");
    __builtin_amdgcn_sched_barrier(0);
    __builtin_amdgcn_s_barrier();
    __builtin_amdgcn_sched_barrier(0);
}

// ---------- prep: combined mask/offset table (k order) + bf16 W ----------
__global__ __launch_bounds__(256) void prep_tables(
    const float* __restrict__ fm, const float* __restrict__ W,
    const int* __restrict__ s_in, float* __restrict__ ws)
{
    int idx = blockIdx.x * 256 + threadIdx.x;   // 16 blocks -> 4096
    if (idx < K_) {
        int jj  = s_in[idx];
        int off = (jj & 63) * 100 + (jj >> 6);          // LDS offset, fits 16 bits
        unsigned mk = (unsigned)f2bf(tanhf(fm[idx]) + 1.0f);
        ((unsigned*)ws)[WS_GM + idx] = (mk << 16) | (unsigned)off;
    }
    if (idx < C_ * D_) ((unsigned short*)(ws + WS_WBF))[idx] = f2bf(W[idx]);
}

// ---------- reduce per-block partials (from d_out scratch) into WS_SUM/WS_SQ ----
// grid 200 x 256: block handles 16 columns; 16-way row split x 32 rows each.
__global__ __launch_bounds__(256) void stats_reduce(
    const float* __restrict__ pbuf, float* __restrict__ ws)
{
    __shared__ float red[256];
    int jq = threadIdx.x & 15;
    int bq = threadIdx.x >> 4;              // 0..15
    int j  = blockIdx.x * 16 + jq;          // 200*16 = 3200 columns
    const float* p = pbuf + (size_t)(bq * 32) * 3200 + j;
    float s = 0.f;
    #pragma unroll 8
    for (int k = 0; k < 32; ++k)
        s += p[(size_t)k * 3200];
    red[threadIdx.x] = s;
    __syncthreads();
    if (bq < 8) red[threadIdx.x] += red[threadIdx.x + 128];
    __syncthreads();
    if (bq < 4) red[threadIdx.x] += red[threadIdx.x + 64];
    __syncthreads();
    if (bq < 2) red[threadIdx.x] += red[threadIdx.x + 32];
    __syncthreads();
    if (bq == 0) ws[WS_SUM + j] = red[jq] + red[jq + 16];
}

// ---------- prep: BN scale/shift/yoff tables in OUTPUT-ELEMENT (rem) order ----
__global__ __launch_bounds__(256) void prep_scale_kernel(
    const float* __restrict__ gamma, const float* __restrict__ beta,
    const int* __restrict__ s_out, float* __restrict__ ws)
{
    int e = blockIdx.x * 256 + threadIdx.x;     // 25 blocks -> 6400
    if (e < 6400) {
        int dd  = e / 100;
        int rem = e - dd * 100;
        int dt  = rem / 25;
        int v   = rem - dt * 25;
        int k   = v * 64 + dd;
        int jj  = s_out[k];
        float mean = ws[WS_SUM + jj] * (1.0f / (float)R_);
        float var  = fmaf(-mean, mean, ws[WS_SQ + jj] * (1.0f / (float)R_));
        float inv  = rsqrtf(var + BN_EPS);
        float sc   = gamma[k] * inv;
        ws[WS_SC2 + e] = sc;
        ws[WS_SH2 + e] = beta[k] - mean * sc;
        ((unsigned*)ws)[WS_YO + e] = (unsigned)((jj & 63) * 100 + dt * 25 + (jj >> 6));
    }
}

// window base pointer: wi in [0, 4800)
__device__ __forceinline__ const float* win_ptr(const float* x0, int wi) {
    int r0 = wi * 4;
    int n  = r0 / 300;
    int t0 = r0 - n * 300;          // t0 % 4 == 0
    return x0 + (size_t)n * 480000 + t0 * 25;
}

// Issue the 4-row window stage as async global->LDS (1600 x 16B).
__device__ __forceinline__ void issue_stage(
    const float* __restrict__ xwin, float4* dst, const int gOff[7], int tid)
{
    const float4* s4 = (const float4*)xwin;
    #pragma unroll
    for (int i = 0; i < 7; ++i) {
        int idx = i * 256 + tid;
        if (idx < 1600)             // wave-uniform guard
            gload16(s4 + gOff[i], dst + idx);
    }
}

// Preload this thread's 28 gather-table entries (same for every window).
__device__ __forceinline__ void load_gmr(
    const unsigned* __restrict__ gmt, unsigned gmr[28], int lane, int w)
{
    int jw = lane & 3;
    int vh = lane >> 4;             // m>>2 where m=lane>>2
    #pragma unroll
    for (int i = 0; i < 14; ++i) {
        int combo = i * 4 + w;      // (T,q2)
        int T  = combo >> 2;
        int q2 = combo & 3;
        int t  = T >> 1;
        int c0 = (T & 1) * 32 + q2 * 8 + jw * 2;
        int v  = t * 4 + vh;
        int kb = (v < V_) ? (v * 64 + c0) : c0;   // clamp padded rows
        gmr[2 * i]     = gmt[kb];
        gmr[2 * i + 1] = gmt[kb + 1];
    }
}

// Build fragment-major bf16 A buffer from staged xs (verified layout).
__device__ __forceinline__ void build_afm(
    const float* xs, unsigned* a_fm32, const unsigned gmr[28], int lane, int w)
{
    int m  = lane >> 2;
    int jw = lane & 3;
    int dt = m & 3;
    #pragma unroll
    for (int i = 0; i < 14; ++i) {
        int combo = i * 4 + w;
        int T  = combo >> 2;
        int q2 = combo & 3;
        unsigned g0 = gmr[2 * i], g1 = gmr[2 * i + 1];
        float m0 = __uint_as_float(g0 & 0xFFFF0000u);
        float m1 = __uint_as_float(g1 & 0xFFFF0000u);
        float f0 = xs[(g0 & 0xFFFFu) + dt * 25] * m0;
        float f1 = xs[(g1 & 0xFFFFu) + dt * 25] * m1;
        a_fm32[(T * 64 + q2 * 16 + m) * 4 + jw] = cvt_pk_bf16(f0, f1);
    }
}

// ---------- pass 1: BN statistics, persistent double-buffered pipeline ----------
__global__ __launch_bounds__(256) void pass1_stats(
    const float* __restrict__ x0, const float* __restrict__ bg,
    const float* __restrict__ ws, float* __restrict__ pbuf)
{
    __shared__ __align__(16) float4 xs2[2][1600];         // 51200 B
    __shared__ __align__(16) unsigned a_fm32[3584];       // 14336 B -> 64 KB total
    const bf16x8* afp = (const bf16x8*)a_fm32;

    int tid = threadIdx.x;
    int lane = tid & 63, w = tid >> 6;
    int l15 = lane & 15, q = lane >> 4;
    int d = w * 16 + l15;

    const unsigned short* Wbf = (const unsigned short*)(ws + WS_WBF);
    bf16x8 bfrag0, bfrag1;
    #pragma unroll
    for (int j = 0; j < 8; ++j) {
        bfrag0[j] = (short)Wbf[(q * 8 + j) * 64 + d];
        bfrag1[j] = (short)Wbf[(32 + q * 8 + j) * 64 + d];
    }
    float breg = bg[d];

    unsigned gmr[28];
    load_gmr((const unsigned*)ws + WS_GM, gmr, lane, w);

    int gOff[7];
    #pragma unroll
    for (int i = 0; i < 7; ++i) {
        int idx = i * 256 + tid;
        int c = idx / 25;
        int r = idx - c * 25;
        gOff[i] = c * 1875 + r;
    }

    float sums[7], sqs[7];
    #pragma unroll
    for (int t = 0; t < 7; ++t) { sums[t] = 0.f; sqs[t] = 0.f; }

    int wi = blockIdx.x;
    int wcount = 0;
    issue_stage(win_ptr(x0, wi), xs2[0], gOff, tid);      // prologue prefetch
    int cur = 0;

    while (true) {
        __syncthreads();              // drains vmcnt: xs2[cur] landed; a_fm free
        int nwi = wi + P1_GRID;
        if (nwi < NWIN)               // prefetch next window into other buffer
            issue_stage(win_ptr(x0, nwi), xs2[cur ^ 1], gOff, tid);

        build_afm((const float*)xs2[cur], a_fm32, gmr, lane, w);
        barrier_lds();                // a_fm visible; prefetch stays in flight
        ++wcount;

        // stats on raw acc; b folded analytically in the epilogue
        #pragma unroll
        for (int t = 0; t < 7; ++t) {
            bf16x8 a0 = afp[(t * 2 + 0) * 64 + lane];
            bf16x8 a1 = afp[(t * 2 + 1) * 64 + lane];
            f32x4 acc = {0.f, 0.f, 0.f, 0.f};
            acc = __builtin_amdgcn_mfma_f32_16x16x32_bf16(a0, bfrag0, acc, 0, 0, 0);
            acc = __builtin_amdgcn_mfma_f32_16x16x32_bf16(a1, bfrag1, acc, 0, 0, 0);
            #pragma unroll
            for (int r = 0; r < 4; ++r) {
                sums[t] += acc[r];
                sqs[t]   = fmaf(acc[r], acc[r], sqs[t]);
            }
        }
        if (nwi >= NWIN) break;
        wi = nwi; cur ^= 1;
    }

    // fold b: sum(a+b) = sum(a)+n*b ; sum((a+b)^2) = sum(a^2)+2b*sum(a)+n*b^2
    float nb = 4.0f * (float)wcount;
    float* pout = pbuf + (size_t)blockIdx.x * 3200;
    #pragma unroll
    for (int t = 0; t < 7; ++t) {
        int v = t * 4 + q;
        if (v < V_) {
            float qf = fmaf(2.0f * breg, sums[t], fmaf(nb * breg, breg, sqs[t]));
            float sf = fmaf(nb, breg, sums[t]);
            __builtin_nontemporal_store(sf, &pout[v * 64 + d]);
            __builtin_nontemporal_store(qf, &pout[1600 + v * 64 + d]);
        }
    }
}

// ---------- pass 2: persistent; recompute y, shift_out, BN affine, resid, ReLU --
// LDS 51200 B -> 3 blocks/CU. Single xs buffer; next window prefetched into xs
// right after build retires (af hoisted to regs; residual re-read from L2-hot x0).
__global__ __launch_bounds__(256, 3) void pass2_out(
    const float* __restrict__ x0, const float* __restrict__ bg,
    const float* __restrict__ ws, float* __restrict__ out)
{
    __shared__ __align__(16) float4 xs4[1600];            // 25600 B
    __shared__ __align__(16) float  yu[6400];             // 25600 B: a_fm then y
    const float* xs = (const float*)xs4;
    unsigned* a_fm32 = (unsigned*)yu;
    const bf16x8* afp = (const bf16x8*)yu;
    float* y_lds = yu;

    int tid = threadIdx.x;
    int lane = tid & 63, w = tid >> 6;
    int l15 = lane & 15, q = lane >> 4;
    int d = w * 16 + l15;

    int gOff[7];
    #pragma unroll
    for (int i = 0; i < 7; ++i) {
        int idx = i * 256 + tid;
        int c = idx / 25;
        int r = idx - c * 25;
        gOff[i] = c * 1875 + r;
    }
    issue_stage(win_ptr(x0, blockIdx.x), xs4, gOff, tid);   // prologue (async)

    // setup overlaps the first stage's flight
    const unsigned short* Wbf = (const unsigned short*)(ws + WS_WBF);
    bf16x8 bfrag0, bfrag1;
    #pragma unroll
    for (int j = 0; j < 8; ++j) {
        bfrag0[j] = (short)Wbf[(q * 8 + j) * 64 + d];
        bfrag1[j] = (short)Wbf[(32 + q * 8 + j) * 64 + d];
    }
    float breg = bg[d];
    unsigned gmr[28];
    load_gmr((const unsigned*)ws + WS_GM, gmr, lane, w);

    const f32x4* sc4 = (const f32x4*)(ws + WS_SC2);
    const f32x4* sh4 = (const f32x4*)(ws + WS_SH2);
    const i32x4* yo4 = (const i32x4*)((const int*)ws + WS_YO);

    int wi = blockIdx.x;
    while (true) {
        __syncthreads();            // xs landed; yu free (prev y-reads retired)
        build_afm(xs, a_fm32, gmr, lane, w);
        __syncthreads();            // all xs reads done; a_fm visible

        int nwi = wi + P2_GRID;
        if (nwi < NWIN)             // overwrite xs under af/MFMA/y/output
            issue_stage(win_ptr(x0, nwi), xs4, gOff, tid);

        bf16x8 af[14];              // hoist A fragments: a_fm region dies here
        #pragma unroll
        for (int t2 = 0; t2 < 14; ++t2)
            af[t2] = afp[t2 * 64 + lane];
        barrier_lds();              // af reads done -> y may overwrite; no vm drain

        #pragma unroll
        for (int t = 0; t < 7; ++t) {
            f32x4 acc = {0.f, 0.f, 0.f, 0.f};
            acc = __builtin_amdgcn_mfma_f32_16x16x32_bf16(af[2 * t],     bfrag0, acc, 0, 0, 0);
            acc = __builtin_amdgcn_mfma_f32_16x16x32_bf16(af[2 * t + 1], bfrag1, acc, 0, 0, 0);
            int v = t * 4 + q;
            if (v < V_) {
                #pragma unroll
                for (int r = 0; r < 4; ++r)
                    y_lds[d * 100 + r * 25 + v] = acc[r] + breg;
            }
        }
        barrier_lds();              // y visible; prefetch still in flight

        // output: tables rem-order (coalesced f4); residual from global (L2-hot:
        // this block staged these exact lines moments ago; same addr as NT store)
        int r0 = wi * 4;
        int n  = r0 / 300;
        int t0 = r0 - n * 300;
        float* outbase = out + (size_t)n * 480000 + t0 * 25;
        const float* inbase = x0 + (size_t)n * 480000 + t0 * 25;
        #pragma unroll
        for (int i = 0; i < 7; ++i) {
            int idx = i * 256 + tid;
            if (idx < 1600) {
                int dd  = idx / 25;
                int pos = idx - dd * 25;
                f32x4 sc = sc4[idx];
                f32x4 sh = sh4[idx];
                i32x4 yo = yo4[idx];
                f32x4 rs = ((const f32x4*)(inbase + dd * 7500))[pos];
                f32x4 o;
                o[0] = fmaxf(fmaf(y_lds[yo[0]], sc[0], sh[0]) + rs[0], 0.f);
                o[1] = fmaxf(fmaf(y_lds[yo[1]], sc[1], sh[1]) + rs[1], 0.f);
                o[2] = fmaxf(fmaf(y_lds[yo[2]], sc[2], sh[2]) + rs[2], 0.f);
                o[3] = fmaxf(fmaf(y_lds[yo[3]], sc[3], sh[3]) + rs[3], 0.f);
                __builtin_nontemporal_store(o, (f32x4*)(outbase + dd * 7500) + pos);
            }
        }
        if (nwi >= NWIN) break;
        wi = nwi;
    }
}

extern "C" void kernel_launch(void* const* d_in, const int* in_sizes, int n_in,
                              void* d_out, int out_size, void* d_ws, size_t ws_size,
                              hipStream_t stream)
{
    const float* x0    = (const float*)d_in[0];
    const float* fm    = (const float*)d_in[1];
    const float* W     = (const float*)d_in[2];
    const float* b     = (const float*)d_in[3];
    const float* gamma = (const float*)d_in[4];
    const float* beta  = (const float*)d_in[5];
    const int*   s_in  = (const int*)d_in[6];
    const int*   s_out = (const int*)d_in[7];
    float* out = (float*)d_out;
    float* ws  = (float*)d_ws;

    prep_tables<<<16, 256, 0, stream>>>(fm, W, s_in, ws);
    // pass1 scribbles partials into d_out; pass2 fully overwrites it afterwards.
    pass1_stats<<<P1_GRID, 256, 0, stream>>>(x0, b, ws, out);
    stats_reduce<<<200, 256, 0, stream>>>(out, ws);
    prep_scale_kernel<<<25, 256, 0, stream>>>(gamma, beta, s_out, ws);
    pass2_out<<<P2_GRID, 256, 0, stream>>>(x0, b, ws, out);
}